// Round 19
// baseline (159.365 us; speedup 1.0000x reference)
//
#include <hip/hip_runtime.h>

typedef unsigned long long u64;
typedef unsigned int u32;

#define NB 64      // graphs
#define NN 128     // nodes per graph
#define NITER 5
#define NGEN 6     // initial labels + 5 WL iterations
#define SALT 0xD1B54A32D192ED03ULL
#define NPAIR_OFF (NB*(NB-1)/2)  // 2016 strict lower pairs
#define TSLOTS 256
#define REP1 10    // in-kernel repeats: stage1
#define REP3 8     // in-kernel repeats: pairs

__device__ __forceinline__ u64 mix64(u64 x) {
    u64 z = x + 0x9E3779B97F4A7C15ULL;
    z = (z ^ (z >> 30)) * 0xBF58476D1CE4E5B9ULL;
    z = (z ^ (z >> 27)) * 0x94D049BB133111EBULL;
    return z ^ (z >> 31);
}

// D1 (R15 structure, body repeated REP1x for slope measurement + profiling).
// 448 blocks x 512 threads: blocks 0..63 writers (full chain -> hgen),
// blocks 64..447 per-(b,gen) table blocks (redundant chain to gen, 256-slot
// {u64,u32} table, SoA export + Kpart). Every rep recomputes identical values.
__global__ __launch_bounds__(512) void wl_stage1(const float* __restrict__ adj,
                                                 const int* __restrict__ labels,
                                                 u64* __restrict__ hgen,
                                                 u64* __restrict__ keysg,
                                                 u32* __restrict__ cntsg,
                                                 float* __restrict__ Kpart,
                                                 float* __restrict__ out) {
    const int blk = blockIdx.x;
    const int t = threadIdx.x;
    const int u = t & 127;   // node
    const int q = t >> 7;    // quarter 0..3
    const bool writer = blk < NB;
    const int b    = writer ? blk   : (blk - NB) / NGEN;
    const int gent = writer ? NITER : (blk - NB) % NGEN;  // iterations to run

    __shared__ u64 gsh[NN];
    __shared__ u64 psum[3][NN];
    __shared__ u64 keys[TSLOTS];
    __shared__ u32 cnts[TSLOTS];
    __shared__ u32 part[4];

    for (int rep = 0; rep < REP1; ++rep) {
        // ---- pack: register adjacency quarter-mask (in-loop: measured) ----
        u32 m = 0;
        if (gent > 0) {
            const float* rowp = adj + ((size_t)b * NN + u) * NN + q * 32;
            #pragma unroll
            for (int k = 0; k < 8; ++k) {
                const float4 v = *(const float4*)(rowp + 4 * k);
                m |= (v.x > 0.5f ? 1u : 0u) << (4 * k);
                m |= (v.y > 0.5f ? 1u : 0u) << (4 * k + 1);
                m |= (v.z > 0.5f ? 1u : 0u) << (4 * k + 2);
                m |= (v.w > 0.5f ? 1u : 0u) << (4 * k + 3);
            }
        }
        u64 h = 0;
        if (q == 0) {
            h = mix64((u64)(u32)labels[b * NN + u]);
            if (writer) hgen[(size_t)b * (NGEN * NN) + u] = h;
        }
        if (t < TSLOTS) { keys[t] = 0ULL; cnts[t] = 0u; }
        __syncthreads();

        for (int it = 0; it < gent; ++it) {
            if (q == 0) gsh[u] = mix64(h ^ SALT);
            __syncthreads();
            u64 s = 0;
            {
                u32 mm = m;
                const u64* gp = gsh + q * 32;
                while (mm) { int j = __builtin_ctz(mm); mm &= mm - 1; s += gp[j]; }
            }
            if (q) psum[q - 1][u] = s;
            __syncthreads();
            if (q == 0) {
                h = mix64(mix64(h) + s + psum[0][u] + psum[1][u] + psum[2][u]);
                if (writer) hgen[(size_t)b * (NGEN * NN) + (it + 1) * NN + u] = h;
            }
        }

        if (!writer) {
            // ---- table build: q0 threads hold the 128 labels in h ----
            if (q == 0) {
                u32 s = (u32)h & (TSLOTS - 1);
                for (;;) {
                    u64 old = atomicCAS((unsigned long long*)&keys[s], 0ULL, h);
                    if (old == 0ULL || old == h) { atomicAdd(&cnts[s], 1u); break; }
                    s = (s + 1) & (TSLOTS - 1);
                }
            }
            __syncthreads();
            const int bg = b * NGEN + gent;
            if (t < TSLOTS) {
                const u64 kk = keys[t];
                const u32 cc = cnts[t];
                keysg[(size_t)bg * TSLOTS + t] = kk;
                cntsg[(size_t)bg * TSLOTS + t] = cc;
                u32 acc = cc * cc;
                #pragma unroll
                for (int off = 32; off > 0; off >>= 1) acc += __shfl_down(acc, off);
                if ((t & 63) == 0) part[t >> 6] = acc;
            }
            __syncthreads();
            if (t == 0) {
                Kpart[bg] = (float)(part[0] + part[1] + part[2] + part[3]);
                if (gent == 0) out[b * NB + b] = 1.0f;
            }
        }
        __syncthreads();   // end-of-rep LDS reuse guard
    }
}

// D2 (R15/R14 structure, body repeated REP3x). 2016 blocks x 256 threads:
// stage b2's 6 tables (18 KiB SoA), probe with b1's 768 labels, normalize.
__global__ __launch_bounds__(256) void wl_pairs(const u64* __restrict__ hgen,
                                                const u64* __restrict__ keysg,
                                                const u32* __restrict__ cntsg,
                                                const float* __restrict__ Kpart,
                                                float* __restrict__ out) {
    const int p = blockIdx.x;
    int b1 = (int)((1.0f + sqrtf(1.0f + 8.0f * (float)p)) * 0.5f);
    while (b1 * (b1 - 1) / 2 > p) --b1;
    while ((b1 + 1) * b1 / 2 <= p) ++b1;
    const int b2 = p - b1 * (b1 - 1) / 2;

    const int t = threadIdx.x;
    __shared__ u64 keys[NGEN * TSLOTS];  // 12 KiB
    __shared__ u32 cnts[NGEN * TSLOTS];  // 6 KiB
    __shared__ u32 part[4];
    __shared__ float dred[2 * NGEN];

    for (int rep = 0; rep < REP3; ++rep) {
        if (t < 2 * NGEN)
            dred[t] = Kpart[(t < NGEN ? b1 : b2) * NGEN + (t % NGEN)];
        {   // stage keys: 768 x ulonglong2 over 256 threads
            const ulonglong2* src = (const ulonglong2*)(keysg + (size_t)b2 * NGEN * TSLOTS);
            ulonglong2* dst = (ulonglong2*)keys;
            #pragma unroll
            for (int k = 0; k < 3; ++k) dst[t + 256 * k] = src[t + 256 * k];
        }
        {   // stage counts: 384 x uint4 over 256 threads
            const uint4* src = (const uint4*)(cntsg + (size_t)b2 * NGEN * TSLOTS);
            uint4* dst = (uint4*)cnts;
            #pragma unroll
            for (int k = 0; k < 2; ++k) {
                const int idx = t + 256 * k;
                if (idx < 384) dst[idx] = src[idx];
            }
        }
        __syncthreads();

        u32 c = 0;
        const u64* abase = hgen + (size_t)b1 * NGEN * NN;
        #pragma unroll
        for (int k = 0; k < 3; ++k) {
            const int idx = t + 256 * k;        // 0..767 -> gen = idx>>7
            const u64 a = abase[idx];
            const int base = (idx >> 7) * TSLOTS;
            u32 s = (u32)a & (TSLOTS - 1);
            for (;;) {
                const u64 kk = keys[base + s];
                if (kk == a) { c += cnts[base + s]; break; }
                if (kk == 0ULL) break;
                s = (s + 1) & (TSLOTS - 1);
            }
        }

        #pragma unroll
        for (int off = 32; off > 0; off >>= 1) c += __shfl_down(c, off);
        if ((t & 63) == 0) part[t >> 6] = c;
        __syncthreads();
        if (t == 0) {
            float d1 = 0.f, d2 = 0.f;
            #pragma unroll
            for (int g = 0; g < NGEN; ++g) { d1 += dred[g]; d2 += dred[NGEN + g]; }
            const float v = (float)(part[0] + part[1] + part[2] + part[3])
                          / (sqrtf(d1) * sqrtf(d2));
            out[b1 * NB + b2] = v;
            out[b2 * NB + b1] = v;
        }
        __syncthreads();   // end-of-rep LDS reuse guard
    }
}

extern "C" void kernel_launch(void* const* d_in, const int* in_sizes, int n_in,
                              void* d_out, int out_size, void* d_ws, size_t ws_size,
                              hipStream_t stream) {
    const float* adj   = (const float*)d_in[0];   // [64,128,128] fp32 (0/1)
    const int*  labels = (const int*)d_in[1];     // [64,128] int32
    float* out = (float*)d_out;                   // [64,64] fp32

    char* ws = (char*)d_ws;
    u64*   hgen  = (u64*)ws;                       // 64*768*8  = 384 KiB
    float* Kpart = (float*)(ws + 448 * 1024);      // 1.5 KiB
    u64*   keysg = (u64*)(ws + 512 * 1024);        // 384*256*8 = 768 KiB
    u32*   cntsg = (u32*)(ws + 1536 * 1024);       // 384*256*4 = 384 KiB

    wl_stage1<<<NB + NB * NGEN, 512, 0, stream>>>(adj, labels, hgen, keysg,
                                                  cntsg, Kpart, out);
    wl_pairs <<<NPAIR_OFF, 256, 0, stream>>>(hgen, keysg, cntsg, Kpart, out);
}

// Round 20
// 26.825 us; speedup vs baseline: 5.9409x; 5.9409x over previous
//
#include <hip/hip_runtime.h>

typedef unsigned long long u64;
typedef unsigned int u32;

#define NB 64      // graphs
#define NN 128     // nodes per graph
#define NITER 5
#define NGEN 6     // initial labels + 5 WL iterations
#define SALT 0xD1B54A32D192ED03ULL
#define NPAIR_OFF (NB*(NB-1)/2)  // 2016 strict lower pairs
#define TSLOTS 256

__device__ __forceinline__ u64 mix64(u64 x) {
    u64 z = x + 0x9E3779B97F4A7C15ULL;
    z = (z ^ (z >> 30)) * 0xBF58476D1CE4E5B9ULL;
    z = (z ^ (z >> 27)) * 0x94D049BB133111EBULL;
    return z ^ (z >> 31);
}

// K1: per-graph WL chain (R7's proven structure). 64 blocks x 512 threads =
// 4 quarter-threads/node; float4 register quarter-masks (pack runs ONCE per
// graph on the whole machine — the 448x-redundant pack was ~1/3 of W1);
// exports u32 labels per generation. Idempotent.
__global__ __launch_bounds__(512) void wl_iter(const float* __restrict__ adj,
                                               const int* __restrict__ labels,
                                               u32* __restrict__ hgen32,
                                               float* __restrict__ out) {
    const int b = blockIdx.x;
    const int t = threadIdx.x;
    const int u = t & 127;   // node
    const int q = t >> 7;    // quarter 0..3

    __shared__ u64 gsh[NN];
    __shared__ u64 psum[3][NN];

    // register adjacency quarter-mask via pipelined float4 loads
    const float* rowp = adj + ((size_t)b * NN + u) * NN + q * 32;
    u32 m = 0;
    #pragma unroll
    for (int k = 0; k < 8; ++k) {
        const float4 v = *(const float4*)(rowp + 4 * k);
        m |= (v.x > 0.5f ? 1u : 0u) << (4 * k);
        m |= (v.y > 0.5f ? 1u : 0u) << (4 * k + 1);
        m |= (v.z > 0.5f ? 1u : 0u) << (4 * k + 2);
        m |= (v.w > 0.5f ? 1u : 0u) << (4 * k + 3);
    }

    u64 h = 0;
    if (q == 0) {
        h = mix64((u64)(u32)labels[b * NN + u]);
        hgen32[(size_t)b * (NGEN * NN) + u] = (u32)h;   // generation 0
        if (u == 0) out[b * NB + b] = 1.0f;
    }

    for (int it = 0; it < NITER; ++it) {
        if (q == 0) gsh[u] = mix64(h ^ SALT);
        __syncthreads();
        u64 s = 0;
        {
            u32 mm = m;
            const u64* gp = gsh + q * 32;
            while (mm) { int j = __builtin_ctz(mm); mm &= mm - 1; s += gp[j]; }
        }
        if (q) psum[q - 1][u] = s;
        __syncthreads();
        if (q == 0) {
            h = mix64(mix64(h) + s + psum[0][u] + psum[1][u] + psum[2][u]);
            hgen32[(size_t)b * (NGEN * NN) + (it + 1) * NN + u] = (u32)h;
        }
    }
}

// K2: per-(graph,generation) compact hash table — 384 blocks x 128 threads.
// {u32 key, u32 cnt} x 256 slots; Kpart[bg] = sum cnt^2 (diag partial).
__global__ __launch_bounds__(128) void wl_tables(const u32* __restrict__ hgen32,
                                                 uint2* __restrict__ tabg,
                                                 float* __restrict__ Kpart) {
    const int bg = blockIdx.x;   // b*NGEN + gen
    const int t = threadIdx.x;

    __shared__ u32 keys[TSLOTS];
    __shared__ u32 cnts[TSLOTS];
    keys[t] = 0u; keys[t + 128] = 0u;
    cnts[t] = 0u; cnts[t + 128] = 0u;
    __syncthreads();

    const u32 h = hgen32[(size_t)bg * NN + t];
    u32 s = h & (TSLOTS - 1);
    for (;;) {
        u32 old = atomicCAS(&keys[s], 0u, h);
        if (old == 0u || old == h) { atomicAdd(&cnts[s], 1u); break; }
        s = (s + 1) & (TSLOTS - 1);
    }
    __syncthreads();

    u32 acc = 0;
    #pragma unroll
    for (int k = 0; k < 2; ++k) {
        const int idx = t + 128 * k;
        const u32 kk = keys[idx];
        const u32 cc = cnts[idx];
        tabg[(size_t)bg * TSLOTS + idx] = make_uint2(kk, cc);
        acc += cc * cc;
    }
    #pragma unroll
    for (int off = 32; off > 0; off >>= 1) acc += __shfl_down(acc, off);
    __shared__ u32 part[2];
    if ((t & 63) == 0) part[t >> 6] = acc;
    __syncthreads();
    if (t == 0) Kpart[bg] = (float)(part[0] + part[1]);
}

// K3: one block per strict lower pair (b1>b2), 256 threads, max parallelism
// (2016 independent blocks — tiling regressed: R16/R18). Stage b2's 6 compact
// tables (12 KiB), probe with b1's 768 u32 labels (coalesced), normalize.
__global__ __launch_bounds__(256) void wl_pairs(const u32* __restrict__ hgen32,
                                                const uint2* __restrict__ tabg,
                                                const float* __restrict__ Kpart,
                                                float* __restrict__ out) {
    const int p = blockIdx.x;
    int b1 = (int)((1.0f + sqrtf(1.0f + 8.0f * (float)p)) * 0.5f);
    while (b1 * (b1 - 1) / 2 > p) --b1;
    while ((b1 + 1) * b1 / 2 <= p) ++b1;
    const int b2 = p - b1 * (b1 - 1) / 2;

    const int t = threadIdx.x;
    __shared__ uint2 tab[NGEN * TSLOTS];  // 12 KiB
    __shared__ u32 red[4];
    __shared__ float dred[2 * NGEN];

    if (t < 2 * NGEN)   // Kdiag partials in parallel
        dred[t] = Kpart[(t < NGEN ? b1 : b2) * NGEN + (t % NGEN)];

    {   // stage b2's tables: 1536 uint2 = 768 uint4 over 256 threads
        const uint4* src = (const uint4*)(tabg + (size_t)b2 * NGEN * TSLOTS);
        uint4* dst = (uint4*)tab;
        #pragma unroll
        for (int k = 0; k < 3; ++k) dst[t + 256 * k] = src[t + 256 * k];
    }
    __syncthreads();

    u32 c = 0;
    const u32* la = hgen32 + (size_t)b1 * (NGEN * NN);
    #pragma unroll
    for (int k = 0; k < 3; ++k) {
        const int idx = t + 256 * k;        // 0..767 -> gen = idx>>7
        const u32 a = la[idx];
        const int base = (idx >> 7) * TSLOTS;
        u32 s = a & (TSLOTS - 1);
        for (;;) {
            const uint2 kv = tab[base + s];
            if (kv.x == a) { c += kv.y; break; }
            if (kv.x == 0u) break;
            s = (s + 1) & (TSLOTS - 1);
        }
    }

    #pragma unroll
    for (int off = 32; off > 0; off >>= 1) c += __shfl_down(c, off);
    if ((t & 63) == 0) red[t >> 6] = c;
    __syncthreads();
    if (t == 0) {
        float d1 = 0.f, d2 = 0.f;
        #pragma unroll
        for (int g = 0; g < NGEN; ++g) { d1 += dred[g]; d2 += dred[NGEN + g]; }
        const float v = (float)(red[0] + red[1] + red[2] + red[3])
                      / (sqrtf(d1) * sqrtf(d2));
        out[b1 * NB + b2] = v;
        out[b2 * NB + b1] = v;
    }
}

extern "C" void kernel_launch(void* const* d_in, const int* in_sizes, int n_in,
                              void* d_out, int out_size, void* d_ws, size_t ws_size,
                              hipStream_t stream) {
    const float* adj   = (const float*)d_in[0];   // [64,128,128] fp32 (0/1)
    const int*  labels = (const int*)d_in[1];     // [64,128] int32
    float* out = (float*)d_out;                   // [64,64] fp32

    char* ws = (char*)d_ws;
    u32*   hgen32 = (u32*)ws;                      // 64*768*4  = 192 KiB
    uint2* tabg   = (uint2*)(ws + 256 * 1024);     // 384*256*8 = 768 KiB
    float* Kpart  = (float*)(ws + 1536 * 1024);    // 1.5 KiB

    wl_iter  <<<NB, 512, 0, stream>>>(adj, labels, hgen32, out);
    wl_tables<<<NB * NGEN, 128, 0, stream>>>(hgen32, tabg, Kpart);
    wl_pairs <<<NPAIR_OFF, 256, 0, stream>>>(hgen32, tabg, Kpart, out);
}